// Round 1
// baseline (263.179 us; speedup 1.0000x reference)
//
#include <hip/hip_runtime.h>
#include <math.h>

// SIF node: x [T=256, H=256, W=256, C=3] fp32 -> out [256,256,3] fp32.
// Per pixel: sequential IF scan over T (mem += x; if mem>1: count++, mem=0),
// then out = pow(count/256, 1/2.2).
//
// Layout note: T is the outermost axis, so thread-per-pixel gives fully
// coalesced loads at every t step (wave reads 256 contiguous bytes).

#define T_STEPS 256
#define NPIX (256 * 256 * 3)

__global__ __launch_bounds__(256) void sif_kernel(const float* __restrict__ x,
                                                  float* __restrict__ out) {
    const int pix = blockIdx.x * blockDim.x + threadIdx.x;
    if (pix >= NPIX) return;

    const float* __restrict__ p = x + pix;

    float mem = 0.0f;
    float cnt = 0.0f;

    // Loads are address-data-independent -> unroll so multiple global loads
    // stay in flight per thread (latency hiding on top of 12 waves/CU TLP).
#pragma unroll 8
    for (int t = 0; t < T_STEPS; ++t) {
        const float v = p[(size_t)t * NPIX];
        mem += v;                       // same fp32 add order as the JAX scan
        const bool fire = mem > 1.0f;   // F.threshold(mem,1,0) + spike>eps
        cnt += fire ? 1.0f : 0.0f;
        mem  = fire ? 0.0f : mem;       // soft reset subtracts full membrane
    }

    const float y = cnt * (1.0f / 256.0f);
    // pow(0, 1/2.2) == 0, powf handles it; counts are small ints so powf
    // accuracy is far inside the 1.35e-2 absmax threshold.
    out[pix] = powf(y, 1.0f / 2.2f);
}

extern "C" void kernel_launch(void* const* d_in, const int* in_sizes, int n_in,
                              void* d_out, int out_size, void* d_ws, size_t ws_size,
                              hipStream_t stream) {
    const float* x = (const float*)d_in[0];
    float* out = (float*)d_out;

    const int threads = 256;
    const int blocks = NPIX / threads;  // 768
    sif_kernel<<<blocks, threads, 0, stream>>>(x, out);
}

// Round 2
// 261.917 us; speedup vs baseline: 1.0048x; 1.0048x over previous
//
#include <hip/hip_runtime.h>
#include <math.h>

// SIF node: x [T=256, H=256, W=256, C=3] fp32 -> out [256,256,3] fp32.
// Per pixel: sequential IF scan over T (mem += x; if mem>1: count++, mem=0),
// then out = pow(count/256, 1/2.2).
//
// Memory-bound streaming op (201 MB read once -> ~32 us floor @6.3 TB/s).
// Round-1 lesson: scalar dword loads + pragma-unroll gave only ~1 load/wave
// in flight (765 GB/s). This version forces MLP explicitly:
//   - float4 loads (16 B/lane, 1 KB/wave/instr)
//   - 2-bank register pipeline: prefetch the next 8 float4 while computing
//     the current 8 (static indices only -> stays in VGPRs)
//   - 768 blocks x 64 threads = 3 waves/CU, ~24 KB/CU in flight.

#define T_STEPS 256
#define NPIX (256 * 256 * 3)
#define NV (NPIX / 4)   // 49152 float4 lanes of work
#define PF 8            // prefetch depth (chunk of t-steps)

__device__ __forceinline__ void sif_step(float4& mem, float4& cnt, float4 v) {
    // Per-component independent IF update, bit-identical fp32 order vs ref.
    mem.x += v.x; mem.y += v.y; mem.z += v.z; mem.w += v.w;
    bool fx = mem.x > 1.0f, fy = mem.y > 1.0f, fz = mem.z > 1.0f, fw = mem.w > 1.0f;
    cnt.x += fx ? 1.0f : 0.0f; cnt.y += fy ? 1.0f : 0.0f;
    cnt.z += fz ? 1.0f : 0.0f; cnt.w += fw ? 1.0f : 0.0f;
    mem.x = fx ? 0.0f : mem.x; mem.y = fy ? 0.0f : mem.y;
    mem.z = fz ? 0.0f : mem.z; mem.w = fw ? 0.0f : mem.w;
}

__global__ __launch_bounds__(64) void sif_kernel(const float* __restrict__ x,
                                                 float* __restrict__ out) {
    const int gid = blockIdx.x * blockDim.x + threadIdx.x;  // 0..NV-1
    const float4* __restrict__ p = reinterpret_cast<const float4*>(x) + gid;

    float4 mem = make_float4(0.f, 0.f, 0.f, 0.f);
    float4 cnt = make_float4(0.f, 0.f, 0.f, 0.f);

    float4 a[PF], b[PF];

    // Prologue: load t = 0..7. Index math stays in 32-bit (max 12.6M < 2^31).
#pragma unroll
    for (int k = 0; k < PF; ++k) a[k] = p[k * NV];

    for (int tb = 0; tb < T_STEPS / PF; ++tb) {
        // Issue next bank's 8 loads FIRST (independent of a's compute) so
        // they stay in flight under the compute below.
        if (tb + 1 < T_STEPS / PF) {
            const int base = (tb + 1) * PF;
#pragma unroll
            for (int k = 0; k < PF; ++k) b[k] = p[(base + k) * NV];
        }
        // Compute on the current bank (no dependence on the b loads).
#pragma unroll
        for (int k = 0; k < PF; ++k) sif_step(mem, cnt, a[k]);
        // Rotate banks (static indices; compiler renames, no real moves).
#pragma unroll
        for (int k = 0; k < PF; ++k) a[k] = b[k];
    }

    const float g = 1.0f / 2.2f;
    float4 r;
    r.x = powf(cnt.x * (1.0f / 256.0f), g);
    r.y = powf(cnt.y * (1.0f / 256.0f), g);
    r.z = powf(cnt.z * (1.0f / 256.0f), g);
    r.w = powf(cnt.w * (1.0f / 256.0f), g);
    reinterpret_cast<float4*>(out)[gid] = r;
}

extern "C" void kernel_launch(void* const* d_in, const int* in_sizes, int n_in,
                              void* d_out, int out_size, void* d_ws, size_t ws_size,
                              hipStream_t stream) {
    const float* x = (const float*)d_in[0];
    float* out = (float*)d_out;

    const int threads = 64;           // 1 wave/block -> fine-grained balance
    const int blocks = NV / threads;  // 768 blocks = 3 waves/CU
    sif_kernel<<<blocks, threads, 0, stream>>>(x, out);
}